// Round 18
// baseline (181.826 us; speedup 1.0000x reference)
//
#include <hip/hip_runtime.h>
#include <math.h>

#define BN 32
#define NPTS 2048
#define MPTS 2048
#define ITERS 5
#define LOG2E 1.44269504088896340736f
#define SHIFT_C 14.0f              // log2 headroom so P=2^(C-log2e*d^2) fits f16

typedef _Float16 v8h __attribute__((ext_vector_type(8)));
typedef _Float16 v4h __attribute__((ext_vector_type(4)));
typedef __fp16   f16x2 __attribute__((ext_vector_type(2)));
typedef float    v4f __attribute__((ext_vector_type(4)));

// ws layout (floats):
//  TS_OFF   [0, 6*192)        T chain: slot k = per-batch affine after k updates
//  PART_OFF [2048, ...)       partial Kabsch sums [ITERS][BN][16][8], plain stores
#define TS_OFF   0
#define PART_OFF 2048

// Closed-form 2x2 Kabsch from summed acc (a8[8]); composes onto (c,s,tx,ty).
__device__ __forceinline__ void kabsch_compose(const float* a8,
                                               float& Tc, float& Ts,
                                               float& Ttx, float& Tty) {
    const float Ssx = a8[0], Ssy = a8[1], Stcx = a8[2], Stcy = a8[3];
    const float Sxx = a8[4], Sxy = a8[5], Syx = a8[6], Syy = a8[7];
    const float invN = 1.0f / (float)NPTS;
    const float csx = Ssx * invN, csy = Ssy * invN;
    const float ctx = Stcx * invN, cty = Stcy * invN;
    const float Hxx = Sxx - Ssx * ctx;
    const float Hxy = Sxy - Ssx * cty;
    const float Hyx = Syx - Ssy * ctx;
    const float Hyy = Syy - Ssy * cty;
    // A = H^T ; R_delta = polar(A) = V U^T
    const float a = Hxx, bb = Hyx, cc = Hxy, d = Hyy;
    const float det = a * d - bb * cc;
    const bool refl = (det < 0.f);
    const float xr = refl ? (a - d) : (a + d);
    const float yr = refl ? (bb + cc) : (cc - bb);
    const float r = fmaxf(sqrtf(xr * xr + yr * yr), 1e-30f);
    const float R00 = xr / r, R10 = yr / r;
    const float R01 = refl ? R10 : -R10;
    const float R11 = refl ? -R00 : R00;
    const float tdx = ctx - (R00 * csx + R01 * csy);
    const float tdy = cty - (R10 * csx + R11 * csy);
    const float cD = R00, sD = R10;      // cos/sin(delta_theta)
    const float nC  = cD * Tc - sD * Ts;
    const float nS  = sD * Tc + cD * Ts;
    const float nTx = cD * Ttx - sD * Tty + tdx;
    const float nTy = sD * Ttx + cD * Tty + tdy;
    Tc = nC; Ts = nS; Ttx = nTx; Tty = nTy;
}

// ---------------------------------------------------------------------------
// One ICP soft-assign pass. Grid 512 x 1024 = 2 blocks/CU (32 waves/CU, 8
// waves/SIMD; VGPR capped at 64 by launch_bounds). Block = batch b
// (blockIdx&31), 128-row group gg (blockIdx>>5). 16 waves: rg=wv>>3 row-group
// (64 rows at g=gg*2+rg), wq=wv&7 m-eighth (16 target tiles).
// Fully-unrolled 16-tile register pipeline (ds prefetch depth 2, D1 MFMA one
// tile ahead; unroll renames all rotations).
// Per tile: D1 = mfma_16x16x32_f16(a1, B1[nt], 0)   // scores (fp32)
//           P  = pkrtz(exp2(D1))                     // f16; D-layout==B-layout
//           D2 = mfma_16x16x16_f16(a2, P, D2)        // rows 0..2 = den, ax, ay
// ---------------------------------------------------------------------------
__global__ __launch_bounds__(1024, 8) void icp_pass(const float* __restrict__ source,
                                                    const float* __restrict__ target,
                                                    const float* __restrict__ init_t,
                                                    float* __restrict__ ws,
                                                    int iter) {
    __shared__ v8h A1s[2050];            // 2048 payload + [2048]=const11 [2049]=zero
    __shared__ v8h A2s[516];             // 512 payload + [512]=ones4 [513]=zero
    __shared__ float4 comb[16][4][16];
    __shared__ float red[2][8];
    __shared__ float shT[6];
    __shared__ float pacc[128];
    const int tid = threadIdx.x;
    const int wv  = tid >> 6;
    const int l   = tid & 63;
    const int q   = l >> 4;
    const int col = l & 15;
    const int wq  = wv & 7;              // m-eighth (16 tiles)
    const int rg  = wv >> 3;             // row-group within block (0..1)
    const int b   = blockIdx.x & 31;     // batch
    const int gg  = blockIdx.x >> 5;     // 128-row group (0..15)
    const int g   = gg * 2 + rg;         // 64-row group (0..31)

    const _Float16 h0 = (_Float16)0.0f;
    const _Float16 h1 = (_Float16)1.0f;

    // ---- build LDS payloads directly from target ----
    const float2* tg = (const float2*)target + b * MPTS;
#pragma unroll
    for (int i = 0; i < 2; ++i) {
        const int m = tid + i * 1024;
        const float2 k = tg[m];
        const float bm = -LOG2E * fmaf(k.x, k.x, k.y * k.y);
        const _Float16 kxh = (_Float16)k.x;
        const _Float16 kxl = (_Float16)(k.x - (float)kxh);
        const _Float16 kyh = (_Float16)k.y;
        const _Float16 kyl = (_Float16)(k.y - (float)kyh);
        const _Float16 bmh = (_Float16)bm;
        const _Float16 bml = (_Float16)(bm - (float)bmh);
        A1s[m] = (v8h){kxh, kxh, kxl, kyh, kyh, kyl, bmh, bml};
    }
    if (tid < 512) {                     // A2: entry e holds kx/ky of targets 4e..4e+3
        const int e = tid;
        const float2 k0 = tg[e * 4 + 0];
        const float2 k1 = tg[e * 4 + 1];
        const float2 k2 = tg[e * 4 + 2];
        const float2 k3 = tg[e * 4 + 3];
        A2s[e] = (v8h){(_Float16)k0.x, (_Float16)k1.x, (_Float16)k2.x, (_Float16)k3.x,
                       (_Float16)k0.y, (_Float16)k1.y, (_Float16)k2.y, (_Float16)k3.y};
    }
    if (tid == 0) {
        A1s[2048] = (v8h){h1, h1, h0, h0, h0, h0, h0, h0};
        A1s[2049] = (v8h){h0, h0, h0, h0, h0, h0, h0, h0};
        A2s[512]  = (v8h){h1, h1, h1, h1, h0, h0, h0, h0};
        A2s[513]  = (v8h){h0, h0, h0, h0, h0, h0, h0, h0};
    }

    // ---- prologue: T for this pass ----
    if (iter == 0) {
        if (tid == 0) {
            const float th = init_t[b * 3 + 0];
            const float c = cosf(th), s = sinf(th);
            shT[0] = c; shT[1] = -s; shT[2] = init_t[b * 3 + 1];
            shT[3] = s; shT[4] = c;  shT[5] = init_t[b * 3 + 2];
            float* Tw = ws + TS_OFF + b * 6;         // T slot 0
            Tw[0] = shT[0]; Tw[1] = shT[1]; Tw[2] = shT[2];
            Tw[3] = shT[3]; Tw[4] = shT[4]; Tw[5] = shT[5];
        }
    } else {
        if (tid < 128)                                // load prev partials (16 slots x 8)
            pacc[tid] = ws[PART_OFF + (size_t)(iter - 1) * BN * 128 + b * 128 + tid];
        __syncthreads();
        if (tid == 0) {
            float a8[8];
#pragma unroll
            for (int j = 0; j < 8; ++j) {
                float s = 0.f;
#pragma unroll
                for (int s16 = 0; s16 < 16; ++s16) s += pacc[s16 * 8 + j];
                a8[j] = s;
            }
            const float* Tp = ws + TS_OFF + (iter - 1) * 192 + b * 6;
            float Tc = Tp[0], Ts = Tp[3], Ttx = Tp[2], Tty = Tp[5];
            kabsch_compose(a8, Tc, Ts, Ttx, Tty);
            shT[0] = Tc; shT[1] = -Ts; shT[2] = Ttx;
            shT[3] = Ts; shT[4] = Tc;  shT[5] = Tty;
            float* Tw = ws + TS_OFF + iter * 192 + b * 6;   // all blocks: same values
            Tw[0] = Tc; Tw[1] = -Ts; Tw[2] = Ttx;
            Tw[3] = Ts; Tw[4] = Tc;  Tw[5] = Tty;
        }
    }
    __syncthreads();
    const float r00 = shT[0], r01 = shT[1], tx = shT[2];
    const float r10 = shT[3], r11 = shT[4], ty = shT[5];

    // ---- B1 frags for this wave's 4 n-tiles ----
    v8h B1[4];
#pragma unroll
    for (int nt = 0; nt < 4; ++nt) {
        const int row = g * 64 + nt * 16 + col;
        const float2 sp = ((const float2*)source)[b * NPTS + row];
        const float sx = fmaf(r00, sp.x, fmaf(r01, sp.y, tx));
        const float sy = fmaf(r10, sp.x, fmaf(r11, sp.y, ty));
        const float qpx = 2.0f * LOG2E * sx;
        const float qpy = 2.0f * LOG2E * sy;
        const float rc  = SHIFT_C - LOG2E * fmaf(sx, sx, sy * sy);
        const _Float16 qpxh = (_Float16)qpx;
        const _Float16 qpxl = (_Float16)(qpx - (float)qpxh);
        const _Float16 qpyh = (_Float16)qpy;
        const _Float16 qpyl = (_Float16)(qpy - (float)qpyh);
        const _Float16 rch  = (_Float16)rc;
        const _Float16 rcl  = (_Float16)(rc - (float)rch);
        v8h f;
        if (q == 0)      f = (v8h){qpxh, qpxl, qpxh, qpyh, qpyl, qpyh, h1, h1};
        else if (q == 1) f = (v8h){rch, rcl, h0, h0, h0, h0, h0, h0};
        else             f = (v8h){h0, h0, h0, h0, h0, h0, h0, h0};
        B1[nt] = f;
    }
    __syncthreads();

    // ---- per-lane LDS addressing: base + t*step; const lanes step 0 ----
    const char* A1c = (const char*)A1s;
    const char* A2c = (const char*)A2s;
    int ad1 = (q == 0) ? (wq * 256 + col) * 16 : ((q == 1) ? 2048 * 16 : 2049 * 16);
    const int st1 = (q == 0) ? 256 : 0;          // +16 targets per tile
    int ad2 = (col == 1) ? (wq * 1024 + q * 16)
            : (col == 2) ? (wq * 1024 + q * 16 + 8)
            : ((col == 0) ? 512 * 16 : 513 * 16);
    const int st2 = (col == 1 || col == 2) ? 64 : 0;
    const v4f zero4 = (v4f){0.f, 0.f, 0.f, 0.f};

    v4f D2[4];
#pragma unroll
    for (int nt = 0; nt < 4; ++nt) D2[nt] = zero4;

    // ---- fully-unrolled 16-tile pipeline ----
    v8h a1w[16];
    v4h a2w[16];
    v4f D1w[16][4];
    a1w[0] = *(const v8h*)(A1c + ad1); a2w[0] = *(const v4h*)(A2c + ad2);
    ad1 += st1; ad2 += st2;
    a1w[1] = *(const v8h*)(A1c + ad1); a2w[1] = *(const v4h*)(A2c + ad2);
    ad1 += st1; ad2 += st2;
#pragma unroll
    for (int nt = 0; nt < 4; ++nt)
        D1w[0][nt] = __builtin_amdgcn_mfma_f32_16x16x32_f16(a1w[0], B1[nt], zero4, 0, 0, 0);

#pragma unroll
    for (int t = 0; t < 16; ++t) {
        if (t < 14) {                        // ds prefetch depth 2
            a1w[t + 2] = *(const v8h*)(A1c + ad1);
            a2w[t + 2] = *(const v4h*)(A2c + ad2);
            ad1 += st1; ad2 += st2;
        }
        if (t < 15) {                        // score tile t+1 ahead of consuming t
#pragma unroll
            for (int nt = 0; nt < 4; ++nt)
                D1w[t + 1][nt] = __builtin_amdgcn_mfma_f32_16x16x32_f16(a1w[t + 1], B1[nt], zero4, 0, 0, 0);
        }
        // consume tile t: 16 exps batched, then pack + accumulate
        float e[16];
#pragma unroll
        for (int nt = 0; nt < 4; ++nt)
#pragma unroll
            for (int j = 0; j < 4; ++j)
                e[nt * 4 + j] = __builtin_amdgcn_exp2f(D1w[t][nt][j]);
#pragma unroll
        for (int nt = 0; nt < 4; ++nt) {
            union { v4h v; f16x2 h[2]; } u;
            u.h[0] = __builtin_amdgcn_cvt_pkrtz(e[nt * 4 + 0], e[nt * 4 + 1]);
            u.h[1] = __builtin_amdgcn_cvt_pkrtz(e[nt * 4 + 2], e[nt * 4 + 3]);
            D2[nt] = __builtin_amdgcn_mfma_f32_16x16x16f16(a2w[t], u.v, D2[nt], 0, 0, 0);
        }
    }

    // ---- combine the 8 m-eighths within each row-group ----
    if (l < 16) {
#pragma unroll
        for (int nt = 0; nt < 4; ++nt)
            comb[wv][nt][col] = make_float4(D2[nt][0], D2[nt][1], D2[nt][2], 0.f);
    }
    __syncthreads();
    float den = 0.f, ax = 0.f, ay = 0.f;
#pragma unroll
    for (int w = 0; w < 8; ++w) {
        const float4 p = comb[rg * 8 + w][q][col];
        den += p.x; ax += p.y; ay += p.z;
    }
    const float tcx = ax / den;
    const float tcy = ay / den;
    const int erow = g * 64 + q * 16 + col;
    const float2 sp = ((const float2*)source)[b * NPTS + erow];
    const float sx = fmaf(r00, sp.x, fmaf(r01, sp.y, tx));
    const float sy = fmaf(r10, sp.x, fmaf(r11, sp.y, ty));
    float v[8] = {sx, sy, tcx, tcy, sx * tcx, sx * tcy, sy * tcx, sy * tcy};
#pragma unroll
    for (int off = 32; off > 0; off >>= 1) {
#pragma unroll
        for (int j = 0; j < 8; ++j) v[j] += __shfl_xor(v[j], off, 64);
    }
    if (l == 0 && wq == 0) {                 // wv = rg*8: one writer per row-group
#pragma unroll
        for (int j = 0; j < 8; ++j) red[rg][j] = v[j];
    }
    __syncthreads();
    if (tid < 2) {                           // block's own slot, 2x float4 store
        float4* slot = (float4*)(ws + PART_OFF + (size_t)iter * BN * 128 + b * 128 + gg * 8);
        slot[tid] = make_float4(red[0][tid * 4 + 0] + red[1][tid * 4 + 0],
                                red[0][tid * 4 + 1] + red[1][tid * 4 + 1],
                                red[0][tid * 4 + 2] + red[1][tid * 4 + 2],
                                red[0][tid * 4 + 3] + red[1][tid * 4 + 3]);
    }
}

// Finisher: apply the last update (partials of pass ITERS-1) and write out.
__global__ __launch_bounds__(64) void icp_finish(float* __restrict__ out,
                                                 const float* __restrict__ ws) {
    const int b = threadIdx.x;
    if (b >= BN) return;
    const float* base = ws + PART_OFF + (size_t)(ITERS - 1) * BN * 128 + b * 128;
    float a8[8] = {0.f, 0.f, 0.f, 0.f, 0.f, 0.f, 0.f, 0.f};
    for (int s16 = 0; s16 < 16; ++s16)
#pragma unroll
        for (int j = 0; j < 8; ++j) a8[j] += base[s16 * 8 + j];
    const float* Tp = ws + TS_OFF + (ITERS - 1) * 192 + b * 6;
    float Tc = Tp[0], Ts = Tp[3], Ttx = Tp[2], Tty = Tp[5];
    kabsch_compose(a8, Tc, Ts, Ttx, Tty);
    out[b * 3 + 0] = atan2f(Ts, Tc);
    out[b * 3 + 1] = Ttx;
    out[b * 3 + 2] = Tty;
}

extern "C" void kernel_launch(void* const* d_in, const int* in_sizes, int n_in,
                              void* d_out, int out_size, void* d_ws, size_t ws_size,
                              hipStream_t stream) {
    const float* source = (const float*)d_in[0];
    const float* target = (const float*)d_in[1];
    const float* initt  = (const float*)d_in[2];
    float* out = (float*)d_out;
    float* ws  = (float*)d_ws;

    for (int k = 0; k < ITERS; ++k)
        icp_pass<<<BN * 16, 1024, 0, stream>>>(source, target, initt, ws, k);
    icp_finish<<<1, 64, 0, stream>>>(out, ws);
}

// Round 19
// 153.916 us; speedup vs baseline: 1.1813x; 1.1813x over previous
//
#include <hip/hip_runtime.h>
#include <math.h>

#define BN 32
#define NPTS 2048
#define MPTS 2048
#define ITERS 5
#define LOG2E 1.44269504088896340736f
#define SHIFT_C 14.0f              // log2 headroom so P=2^(C-log2e*d^2) fits f16

typedef _Float16 v8h __attribute__((ext_vector_type(8)));
typedef _Float16 v4h __attribute__((ext_vector_type(4)));
typedef __fp16   f16x2 __attribute__((ext_vector_type(2)));
typedef float    v4f __attribute__((ext_vector_type(4)));

// ws layout (floats):
//  TS_OFF   [0, 6*192)        T chain: slot k = per-batch affine after k updates
//  PART_OFF [2048, ...)       partial Kabsch sums [ITERS][BN][8][8], plain stores
#define TS_OFF   0
#define PART_OFF 2048

// Closed-form 2x2 Kabsch from summed acc (a8[8]); composes onto (c,s,tx,ty).
__device__ __forceinline__ void kabsch_compose(const float* a8,
                                               float& Tc, float& Ts,
                                               float& Ttx, float& Tty) {
    const float Ssx = a8[0], Ssy = a8[1], Stcx = a8[2], Stcy = a8[3];
    const float Sxx = a8[4], Sxy = a8[5], Syx = a8[6], Syy = a8[7];
    const float invN = 1.0f / (float)NPTS;
    const float csx = Ssx * invN, csy = Ssy * invN;
    const float ctx = Stcx * invN, cty = Stcy * invN;
    const float Hxx = Sxx - Ssx * ctx;
    const float Hxy = Sxy - Ssx * cty;
    const float Hyx = Syx - Ssy * ctx;
    const float Hyy = Syy - Ssy * cty;
    // A = H^T ; R_delta = polar(A) = V U^T
    const float a = Hxx, bb = Hyx, cc = Hxy, d = Hyy;
    const float det = a * d - bb * cc;
    const bool refl = (det < 0.f);
    const float xr = refl ? (a - d) : (a + d);
    const float yr = refl ? (bb + cc) : (cc - bb);
    const float r = fmaxf(sqrtf(xr * xr + yr * yr), 1e-30f);
    const float R00 = xr / r, R10 = yr / r;
    const float R01 = refl ? R10 : -R10;
    const float R11 = refl ? -R00 : R00;
    const float tdx = ctx - (R00 * csx + R01 * csy);
    const float tdy = cty - (R10 * csx + R11 * csy);
    const float cD = R00, sD = R10;      // cos/sin(delta_theta)
    const float nC  = cD * Tc - sD * Ts;
    const float nS  = sD * Tc + cD * Ts;
    const float nTx = cD * Ttx - sD * Tty + tdx;
    const float nTy = sD * Ttx + cD * Tty + tdy;
    Tc = nC; Ts = nS; Ttx = nTx; Tty = nTy;
}

// ---------------------------------------------------------------------------
// One ICP soft-assign pass (prologue folds the previous iteration's T-update).
// Grid 256 x 1024 (1 block/CU, 4 waves/SIMD): block = batch b (blockIdx&31),
// 256-row group gg (blockIdx>>5). 16 waves: rg=wv>>2 row-group (64 rows at
// g=gg*4+rg), wq=wv&3 m-quarter (32 target tiles). Targets staged once per CU
// per pass. Fully-unrolled 32-tile register pipeline (ds prefetch depth 2,
// D1 MFMA one tile ahead; unroll renames all rotations).
// Per tile: D1 = mfma_16x16x32_f16(a1, B1[nt], 0)   // scores (fp32)
//           P  = pkrtz(exp2(D1))                     // f16; D-layout==B-layout
//           D2 = mfma_16x16x16_f16(a2, P, D2)        // rows 0..2 = den, ax, ay
// Measured plateau: pass ~20.5 us, exp-throughput-bound (v_exp shares the
// SIMD issue port — R14); occupancy 3/4/6/8 waves/SIMD all neutral-or-worse.
// ---------------------------------------------------------------------------
__global__ __launch_bounds__(1024, 4) void icp_pass(const float* __restrict__ source,
                                                    const float* __restrict__ target,
                                                    const float* __restrict__ init_t,
                                                    float* __restrict__ ws,
                                                    int iter) {
    __shared__ v8h A1s[2050];            // 2048 payload + [2048]=const11 [2049]=zero
    __shared__ v8h A2s[516];             // 512 payload + [512]=ones4 [513]=zero
    __shared__ float4 comb[16][4][16];
    __shared__ float red[4][8];
    __shared__ float shT[6];
    __shared__ float pacc[64];
    const int tid = threadIdx.x;
    const int wv  = tid >> 6;
    const int l   = tid & 63;
    const int q   = l >> 4;
    const int col = l & 15;
    const int wq  = wv & 3;              // m-quarter (32 tiles)
    const int rg  = wv >> 2;             // row-group within block (0..3)
    const int b   = blockIdx.x & 31;     // batch
    const int gg  = blockIdx.x >> 5;     // 256-row group (0..7)
    const int g   = gg * 4 + rg;         // 64-row group (0..31)

    const _Float16 h0 = (_Float16)0.0f;
    const _Float16 h1 = (_Float16)1.0f;

    // ---- build LDS payloads directly from target (once per CU per pass) ----
    const float2* tg = (const float2*)target + b * MPTS;
#pragma unroll
    for (int i = 0; i < 2; ++i) {
        const int m = tid + i * 1024;
        const float2 k = tg[m];
        const float bm = -LOG2E * fmaf(k.x, k.x, k.y * k.y);
        const _Float16 kxh = (_Float16)k.x;
        const _Float16 kxl = (_Float16)(k.x - (float)kxh);
        const _Float16 kyh = (_Float16)k.y;
        const _Float16 kyl = (_Float16)(k.y - (float)kyh);
        const _Float16 bmh = (_Float16)bm;
        const _Float16 bml = (_Float16)(bm - (float)bmh);
        A1s[m] = (v8h){kxh, kxh, kxl, kyh, kyh, kyl, bmh, bml};
    }
    if (tid < 512) {                     // A2: entry e holds kx/ky of targets 4e..4e+3
        const int e = tid;
        const float2 k0 = tg[e * 4 + 0];
        const float2 k1 = tg[e * 4 + 1];
        const float2 k2 = tg[e * 4 + 2];
        const float2 k3 = tg[e * 4 + 3];
        A2s[e] = (v8h){(_Float16)k0.x, (_Float16)k1.x, (_Float16)k2.x, (_Float16)k3.x,
                       (_Float16)k0.y, (_Float16)k1.y, (_Float16)k2.y, (_Float16)k3.y};
    }
    if (tid == 0) {
        A1s[2048] = (v8h){h1, h1, h0, h0, h0, h0, h0, h0};
        A1s[2049] = (v8h){h0, h0, h0, h0, h0, h0, h0, h0};
        A2s[512]  = (v8h){h1, h1, h1, h1, h0, h0, h0, h0};
        A2s[513]  = (v8h){h0, h0, h0, h0, h0, h0, h0, h0};
    }

    // ---- prologue: T for this pass ----
    if (iter == 0) {
        if (tid == 0) {
            const float th = init_t[b * 3 + 0];
            const float c = cosf(th), s = sinf(th);
            shT[0] = c; shT[1] = -s; shT[2] = init_t[b * 3 + 1];
            shT[3] = s; shT[4] = c;  shT[5] = init_t[b * 3 + 2];
            float* Tw = ws + TS_OFF + b * 6;         // T slot 0
            Tw[0] = shT[0]; Tw[1] = shT[1]; Tw[2] = shT[2];
            Tw[3] = shT[3]; Tw[4] = shT[4]; Tw[5] = shT[5];
        }
    } else {
        if (tid < 64)                                 // load prev partials (8 slots x 8)
            pacc[tid] = ws[PART_OFF + (size_t)(iter - 1) * BN * 64 + b * 64 + tid];
        __syncthreads();
        if (tid == 0) {
            float a8[8];
#pragma unroll
            for (int j = 0; j < 8; ++j) {
                float s = 0.f;
#pragma unroll
                for (int s8 = 0; s8 < 8; ++s8) s += pacc[s8 * 8 + j];
                a8[j] = s;
            }
            const float* Tp = ws + TS_OFF + (iter - 1) * 192 + b * 6;
            float Tc = Tp[0], Ts = Tp[3], Ttx = Tp[2], Tty = Tp[5];
            kabsch_compose(a8, Tc, Ts, Ttx, Tty);
            shT[0] = Tc; shT[1] = -Ts; shT[2] = Ttx;
            shT[3] = Ts; shT[4] = Tc;  shT[5] = Tty;
            float* Tw = ws + TS_OFF + iter * 192 + b * 6;   // all blocks: same values
            Tw[0] = Tc; Tw[1] = -Ts; Tw[2] = Ttx;
            Tw[3] = Ts; Tw[4] = Tc;  Tw[5] = Tty;
        }
    }
    __syncthreads();
    const float r00 = shT[0], r01 = shT[1], tx = shT[2];
    const float r10 = shT[3], r11 = shT[4], ty = shT[5];

    // ---- B1 frags for this wave's 4 n-tiles ----
    v8h B1[4];
#pragma unroll
    for (int nt = 0; nt < 4; ++nt) {
        const int row = g * 64 + nt * 16 + col;
        const float2 sp = ((const float2*)source)[b * NPTS + row];
        const float sx = fmaf(r00, sp.x, fmaf(r01, sp.y, tx));
        const float sy = fmaf(r10, sp.x, fmaf(r11, sp.y, ty));
        const float qpx = 2.0f * LOG2E * sx;
        const float qpy = 2.0f * LOG2E * sy;
        const float rc  = SHIFT_C - LOG2E * fmaf(sx, sx, sy * sy);
        const _Float16 qpxh = (_Float16)qpx;
        const _Float16 qpxl = (_Float16)(qpx - (float)qpxh);
        const _Float16 qpyh = (_Float16)qpy;
        const _Float16 qpyl = (_Float16)(qpy - (float)qpyh);
        const _Float16 rch  = (_Float16)rc;
        const _Float16 rcl  = (_Float16)(rc - (float)rch);
        v8h f;
        if (q == 0)      f = (v8h){qpxh, qpxl, qpxh, qpyh, qpyl, qpyh, h1, h1};
        else if (q == 1) f = (v8h){rch, rcl, h0, h0, h0, h0, h0, h0};
        else             f = (v8h){h0, h0, h0, h0, h0, h0, h0, h0};
        B1[nt] = f;
    }
    __syncthreads();

    // ---- per-lane LDS addressing: base + t*step; const lanes step 0 ----
    const char* A1c = (const char*)A1s;
    const char* A2c = (const char*)A2s;
    int ad1 = (q == 0) ? (wq * 512 + col) * 16 : ((q == 1) ? 2048 * 16 : 2049 * 16);
    const int st1 = (q == 0) ? 256 : 0;
    int ad2 = (col == 1) ? (wq * 2048 + q * 16)
            : (col == 2) ? (wq * 2048 + q * 16 + 8)
            : ((col == 0) ? 512 * 16 : 513 * 16);
    const int st2 = (col == 1 || col == 2) ? 64 : 0;
    const v4f zero4 = (v4f){0.f, 0.f, 0.f, 0.f};

    v4f D2[4];
#pragma unroll
    for (int nt = 0; nt < 4; ++nt) D2[nt] = zero4;

    // ---- fully-unrolled 32-tile pipeline ----
    v8h a1w[32];
    v4h a2w[32];
    v4f D1w[32][4];
    a1w[0] = *(const v8h*)(A1c + ad1); a2w[0] = *(const v4h*)(A2c + ad2);
    ad1 += st1; ad2 += st2;
    a1w[1] = *(const v8h*)(A1c + ad1); a2w[1] = *(const v4h*)(A2c + ad2);
    ad1 += st1; ad2 += st2;
#pragma unroll
    for (int nt = 0; nt < 4; ++nt)
        D1w[0][nt] = __builtin_amdgcn_mfma_f32_16x16x32_f16(a1w[0], B1[nt], zero4, 0, 0, 0);

#pragma unroll
    for (int t = 0; t < 32; ++t) {
        if (t < 30) {                        // ds prefetch depth 2
            a1w[t + 2] = *(const v8h*)(A1c + ad1);
            a2w[t + 2] = *(const v4h*)(A2c + ad2);
            ad1 += st1; ad2 += st2;
        }
        if (t < 31) {                        // score tile t+1 ahead of consuming t
#pragma unroll
            for (int nt = 0; nt < 4; ++nt)
                D1w[t + 1][nt] = __builtin_amdgcn_mfma_f32_16x16x32_f16(a1w[t + 1], B1[nt], zero4, 0, 0, 0);
        }
        // consume tile t: 16 exps batched, then pack + accumulate
        float e[16];
#pragma unroll
        for (int nt = 0; nt < 4; ++nt)
#pragma unroll
            for (int j = 0; j < 4; ++j)
                e[nt * 4 + j] = __builtin_amdgcn_exp2f(D1w[t][nt][j]);
#pragma unroll
        for (int nt = 0; nt < 4; ++nt) {
            union { v4h v; f16x2 h[2]; } u;
            u.h[0] = __builtin_amdgcn_cvt_pkrtz(e[nt * 4 + 0], e[nt * 4 + 1]);
            u.h[1] = __builtin_amdgcn_cvt_pkrtz(e[nt * 4 + 2], e[nt * 4 + 3]);
            D2[nt] = __builtin_amdgcn_mfma_f32_16x16x16f16(a2w[t], u.v, D2[nt], 0, 0, 0);
        }
    }

    // ---- combine the 4 m-quarters within each row-group ----
    if (l < 16) {
#pragma unroll
        for (int nt = 0; nt < 4; ++nt)
            comb[wv][nt][col] = make_float4(D2[nt][0], D2[nt][1], D2[nt][2], 0.f);
    }
    __syncthreads();
    float den = 0.f, ax = 0.f, ay = 0.f;
#pragma unroll
    for (int w = 0; w < 4; ++w) {
        const float4 p = comb[rg * 4 + w][q][col];
        den += p.x; ax += p.y; ay += p.z;
    }
    const float tcx = ax / den;
    const float tcy = ay / den;
    const int erow = g * 64 + q * 16 + col;
    const float2 sp = ((const float2*)source)[b * NPTS + erow];
    const float sx = fmaf(r00, sp.x, fmaf(r01, sp.y, tx));
    const float sy = fmaf(r10, sp.x, fmaf(r11, sp.y, ty));
    float v[8] = {sx, sy, tcx, tcy, sx * tcx, sx * tcy, sy * tcx, sy * tcy};
#pragma unroll
    for (int off = 32; off > 0; off >>= 1) {
#pragma unroll
        for (int j = 0; j < 8; ++j) v[j] += __shfl_xor(v[j], off, 64);
    }
    if (l == 0 && wq == 0) {                 // wv = rg*4: one writer per row-group
#pragma unroll
        for (int j = 0; j < 8; ++j) red[rg][j] = v[j];
    }
    __syncthreads();
    if (tid < 2) {                           // block's own slot, 2x float4 store
        float4* slot = (float4*)(ws + PART_OFF + (size_t)iter * BN * 64 + b * 64 + gg * 8);
        slot[tid] = make_float4(((red[0][tid * 4 + 0] + red[1][tid * 4 + 0]) +
                                 (red[2][tid * 4 + 0] + red[3][tid * 4 + 0])),
                                ((red[0][tid * 4 + 1] + red[1][tid * 4 + 1]) +
                                 (red[2][tid * 4 + 1] + red[3][tid * 4 + 1])),
                                ((red[0][tid * 4 + 2] + red[1][tid * 4 + 2]) +
                                 (red[2][tid * 4 + 2] + red[3][tid * 4 + 2])),
                                ((red[0][tid * 4 + 3] + red[1][tid * 4 + 3]) +
                                 (red[2][tid * 4 + 3] + red[3][tid * 4 + 3])));
    }
}

// Finisher: apply the last update (partials of pass ITERS-1) and write out.
__global__ __launch_bounds__(64) void icp_finish(float* __restrict__ out,
                                                 const float* __restrict__ ws) {
    const int b = threadIdx.x;
    if (b >= BN) return;
    const float* base = ws + PART_OFF + (size_t)(ITERS - 1) * BN * 64 + b * 64;
    float a8[8] = {0.f, 0.f, 0.f, 0.f, 0.f, 0.f, 0.f, 0.f};
    for (int s8 = 0; s8 < 8; ++s8)
#pragma unroll
        for (int j = 0; j < 8; ++j) a8[j] += base[s8 * 8 + j];
    const float* Tp = ws + TS_OFF + (ITERS - 1) * 192 + b * 6;
    float Tc = Tp[0], Ts = Tp[3], Ttx = Tp[2], Tty = Tp[5];
    kabsch_compose(a8, Tc, Ts, Ttx, Tty);
    out[b * 3 + 0] = atan2f(Ts, Tc);
    out[b * 3 + 1] = Ttx;
    out[b * 3 + 2] = Tty;
}

extern "C" void kernel_launch(void* const* d_in, const int* in_sizes, int n_in,
                              void* d_out, int out_size, void* d_ws, size_t ws_size,
                              hipStream_t stream) {
    const float* source = (const float*)d_in[0];
    const float* target = (const float*)d_in[1];
    const float* initt  = (const float*)d_in[2];
    float* out = (float*)d_out;
    float* ws  = (float*)d_ws;

    for (int k = 0; k < ITERS; ++k)
        icp_pass<<<BN * 8, 1024, 0, stream>>>(source, target, initt, ws, k);
    icp_finish<<<1, 64, 0, stream>>>(out, ws);
}